// Round 9
// baseline (455.152 us; speedup 1.0000x reference)
//
#include <hip/hip_runtime.h>
#include <hip/hip_bf16.h>

#define BB 4
#define NN 2048
#define DD 128
#define HH 4
#define LOG2E 1.4426950408889634f
#define NEG_BIG (-1e30f)

typedef __attribute__((ext_vector_type(8))) short bf16x8;     // 8 bf16 in 4 VGPRs
typedef __attribute__((ext_vector_type(4))) short bf16x4;     // 4 bf16 in 2 VGPRs
typedef __attribute__((ext_vector_type(4))) float f32x4;      // MFMA accumulator
typedef __attribute__((ext_vector_type(8))) _Float16 f16x8;   // 8 fp16 in 4 VGPRs
typedef __attribute__((ext_vector_type(4))) _Float16 f16x4;   // 4 fp16 in 2 VGPRs

__device__ __forceinline__ unsigned short f2bf(float f) {
    union { float f; unsigned int u; } v; v.f = f;
    unsigned int r = v.u + 0x7FFF + ((v.u >> 16) & 1);        // round-nearest-even
    return (unsigned short)(r >> 16);
}

// ---------------------------------------------------------------------------
// Kernel PREP: wsv/wdv (score vectors) + WT16[h][o][i] = fp16 transpose of W.
// ---------------------------------------------------------------------------
__global__ __launch_bounds__(128) void k_prep(const float* __restrict__ W,
                                              const float* __restrict__ a,
                                              float* __restrict__ wsv,
                                              float* __restrict__ wdv,
                                              _Float16* __restrict__ WT16) {
    int h = blockIdx.x;
    int i = threadIdx.x;
    const float* Wr  = W + (h * DD + i) * DD;
    const float* as_ = a + h * 2 * DD;
    const float* ad_ = as_ + DD;
    float s = 0.f, d = 0.f;
    for (int o = 0; o < DD; ++o) {
        float w = Wr[o];
        s += w * as_[o];
        d += w * ad_[o];
        WT16[((size_t)h * DD + o) * DD + i] = (_Float16)w;   // coalesced over i
    }
    wsv[h * DD + i] = s;
    wdv[h * DD + i] = d;
}

// ---------------------------------------------------------------------------
// Kernel B: s[b,h,n] = x[b,n,:].wsv[h]; d likewise. fp32 (feeds exponents).
// ---------------------------------------------------------------------------
__global__ __launch_bounds__(256) void k_sd(const float* __restrict__ x,
                                            const float* __restrict__ wsv,
                                            const float* __restrict__ wdv,
                                            float* __restrict__ s_out,
                                            float* __restrict__ d_out_) {
    __shared__ float xs[64 * 129];
    __shared__ float ws[4 * 129], wd[4 * 129];
    int tid = threadIdx.x;
    int b  = blockIdx.x / (NN / 64);
    int nb = (blockIdx.x % (NN / 64)) * 64;
    for (int idx = tid; idx < HH * DD; idx += 256) {
        ws[(idx >> 7) * 129 + (idx & 127)] = wsv[idx];
        wd[(idx >> 7) * 129 + (idx & 127)] = wdv[idx];
    }
    for (int idx = tid; idx < 64 * 128; idx += 256) {
        int r = idx >> 7, c = idx & 127;
        xs[r * 129 + c] = x[((size_t)b * NN + nb + r) * DD + c];
    }
    __syncthreads();
    int h = tid & 3, r = tid >> 2;
    float sv = 0.f, dv = 0.f;
#pragma unroll 8
    for (int i = 0; i < DD; ++i) {
        float xv = xs[r * 129 + i];
        sv += xv * ws[h * 129 + i];
        dv += xv * wd[h * 129 + i];
    }
    int n = nb + r;
    s_out[(b * HH + h) * NN + n] = sv;
    d_out_[(b * HH + h) * NN + n] = dv;
}

// ---------------------------------------------------------------------------
// Kernel H: hT[bh][o][n] (bf16) = (W^T @ x^T) via fp16 MFMA (proven R8).
// ---------------------------------------------------------------------------
__global__ __launch_bounds__(256) void k_h_mfma(const float* __restrict__ x,
                                                const _Float16* __restrict__ WT16,
                                                unsigned short* __restrict__ hT) {
    __shared__ unsigned short wt_lds[128 * 128];   // fp16 bits, swizzled
    __shared__ unsigned short x_lds[64 * 128];     // fp16 bits, swizzled
    int tid = threadIdx.x;
    int bh = blockIdx.x >> 5;                      // NN/64 = 32 n-tiles
    int nb = (blockIdx.x & 31) * 64;
    int b = bh >> 2, h = bh & 3;

    {
        int o = tid >> 1, ihalf = (tid & 1) * 64;
        const _Float16* src = WT16 + ((size_t)h * DD + o) * DD + ihalf;
#pragma unroll
        for (int q = 0; q < 8; ++q) {
            f16x8 v = *(const f16x8*)(src + q * 8);
            int byte = ((ihalf + q * 8) * 2) ^ ((o & 15) << 4);
            *(f16x8*)&wt_lds[o * 128 + (byte >> 1)] = v;
        }
    }
    {
        int n = tid >> 2, iseg = (tid & 3) * 32;
        const float* src = x + ((size_t)b * NN + nb + n) * DD + iseg;
#pragma unroll
        for (int q = 0; q < 8; ++q) {
            float4 v = *(const float4*)(src + q * 4);
            f16x4 p;
            p[0] = (_Float16)v.x; p[1] = (_Float16)v.y;
            p[2] = (_Float16)v.z; p[3] = (_Float16)v.w;
            int byte = ((iseg + q * 4) * 2) ^ ((n & 15) << 4);
            *(f16x4*)&x_lds[n * 128 + (byte >> 1)] = p;
        }
    }
    __syncthreads();

    int l = tid & 63, w = tid >> 6, col = l & 15, quad = l >> 4;
    f32x4 acc[8];
#pragma unroll
    for (int ot = 0; ot < 8; ++ot) acc[ot] = (f32x4){0.f, 0.f, 0.f, 0.f};
#pragma unroll
    for (int k = 0; k < 4; ++k) {
        int cbyte = (k * 64 + quad * 16) ^ (col << 4);
        f16x8 bv = *(const f16x8*)&x_lds[(w * 16 + col) * 128 + (cbyte >> 1)];
#pragma unroll
        for (int ot = 0; ot < 8; ++ot) {
            f16x8 av = *(const f16x8*)&wt_lds[(ot * 16 + col) * 128 + (cbyte >> 1)];
            acc[ot] = __builtin_amdgcn_mfma_f32_16x16x32_f16(av, bv, acc[ot], 0, 0, 0);
        }
    }
    unsigned short* base = hT + (size_t)bh * DD * NN;
#pragma unroll
    for (int ot = 0; ot < 8; ++ot)
#pragma unroll
        for (int r = 0; r < 4; ++r)
            base[(size_t)(ot * 16 + quad * 4 + r) * NN + nb + w * 16 + col] =
                f2bf(acc[ot][r]);
}

// ---------------------------------------------------------------------------
// Kernel DMAX: dmax[bh] = max_m d[bh,m] (valid stabilizer source).
// ---------------------------------------------------------------------------
__global__ __launch_bounds__(256) void k_dmax(const float* __restrict__ d_,
                                              float* __restrict__ dmax_) {
    __shared__ float red[4];
    int bh = blockIdx.x, tid = threadIdx.x;
    const float4* dp = (const float4*)(d_ + (size_t)bh * NN);
    float4 v0 = dp[tid];
    float4 v1 = dp[256 + tid];
    float m = fmaxf(fmaxf(fmaxf(v0.x, v0.y), fmaxf(v0.z, v0.w)),
                    fmaxf(fmaxf(v1.x, v1.y), fmaxf(v1.z, v1.w)));
#pragma unroll
    for (int off = 32; off >= 1; off >>= 1)
        m = fmaxf(m, __shfl_xor(m, off, 64));
    if ((tid & 63) == 0) red[tid >> 6] = m;
    __syncthreads();
    if (tid == 0)
        dmax_[bh] = fmaxf(fmaxf(red[0], red[1]), fmaxf(red[2], red[3]));
}

// ---------------------------------------------------------------------------
// Kernel 3 (MFMA attention). Round-8: 32-ROW TILES -> grid 1024 (4 blocks/CU
// offered; was grid-limited at 2). LDS 40KB (al 8K + hT 32K); AdjD and acc
// halve. Same verified index formulas with rh=w&1 (row half), ch=w>>1
// (col half). R7 VMEM-early ordering kept.
// ---------------------------------------------------------------------------
struct AdjD {
    int4   a4[4];
    float4 d4;
};

__device__ __forceinline__ void adjd_load(int mb, const int* adj_base,
                                          const float* dg, int ac4, AdjD& R) {
#pragma unroll
    for (int p = 0; p < 4; ++p)
        R.a4[p] = *(const int4*)(adj_base + (size_t)(p * 8) * NN + mb);
    R.d4 = *(const float4*)(dg + mb + ac4);
}

__device__ __forceinline__ void p1_accum(const AdjD& R, const float (&sreg)[4],
                                         const float (&Mreg)[4], float (&Lp)[4]) {
#pragma unroll
    for (int p = 0; p < 4; ++p) {
        float sn = sreg[p], Mn = Mreg[p];
        float t0 = sn + R.d4.x, t1 = sn + R.d4.y;
        float t2 = sn + R.d4.z, t3 = sn + R.d4.w;
        float v0 = t0 > 0.f ? t0 : 0.2f * t0;
        float v1 = t1 > 0.f ? t1 : 0.2f * t1;
        float v2 = t2 > 0.f ? t2 : 0.2f * t2;
        float v3 = t3 > 0.f ? t3 : 0.2f * t3;
        float e0 = (R.a4[p].x != 0) ? exp2f((v0 - Mn) * LOG2E) : 0.f;
        float e1 = (R.a4[p].y != 0) ? exp2f((v1 - Mn) * LOG2E) : 0.f;
        float e2 = (R.a4[p].z != 0) ? exp2f((v2 - Mn) * LOG2E) : 0.f;
        float e3 = (R.a4[p].w != 0) ? exp2f((v3 - Mn) * LOG2E) : 0.f;
        Lp[p] += (e0 + e1) + (e2 + e3);
    }
}

template <bool WRITE_ALPHA>
__device__ __forceinline__ void attn_tile_body(
    int mb, AdjD& cur, AdjD& nxt,
    const int* adj_base, const float* dg, int ac4,
    const unsigned short* hbase,
    unsigned short* al_lds, unsigned short* hT_lds,
    const float (&sreg)[4], const float (&Mreg)[4], const float (&Lin)[4],
    float* alpha_base, int ar0, int hrow0, int hbyte,
    int rh, int ch, int col, int quad, f32x4 (&acc)[4])
{
    // ---- issue ALL VMEM for this iteration up front (phase A covers it) ----
    bf16x8 hv[8];
#pragma unroll
    for (int q = 0; q < 8; ++q)
        hv[q] = *(const bf16x8*)(hbase + (size_t)(q * 16) * NN + mb);
    adjd_load((mb + 128) & (NN - 1), adj_base, dg, ac4, nxt);

    // ---- phase A: alpha (bf16 -> LDS swizzled; fp32 -> coalesced store) ----
#pragma unroll
    for (int p = 0; p < 4; ++p) {
        int row = p * 8 + ar0;
        float sn = sreg[p], Mn = Mreg[p], Li = Lin[p];
        float t0 = sn + cur.d4.x, t1 = sn + cur.d4.y;
        float t2 = sn + cur.d4.z, t3 = sn + cur.d4.w;
        float v0 = t0 > 0.f ? t0 : 0.2f * t0;
        float v1 = t1 > 0.f ? t1 : 0.2f * t1;
        float v2 = t2 > 0.f ? t2 : 0.2f * t2;
        float v3 = t3 > 0.f ? t3 : 0.2f * t3;
        float e0 = (cur.a4[p].x != 0) ? exp2f((v0 - Mn) * LOG2E) * Li : 0.f;
        float e1 = (cur.a4[p].y != 0) ? exp2f((v1 - Mn) * LOG2E) * Li : 0.f;
        float e2 = (cur.a4[p].z != 0) ? exp2f((v2 - Mn) * LOG2E) * Li : 0.f;
        float e3 = (cur.a4[p].w != 0) ? exp2f((v3 - Mn) * LOG2E) * Li : 0.f;
        bf16x4 pk;
        pk[0] = (short)f2bf(e0); pk[1] = (short)f2bf(e1);
        pk[2] = (short)f2bf(e2); pk[3] = (short)f2bf(e3);
        int abyte = (ac4 * 2) ^ ((row & 15) << 4);      // swizzled byte-in-row
        *(bf16x4*)&al_lds[row * 128 + (abyte >> 1)] = pk;
        if (WRITE_ALPHA) {
            float4 ev; ev.x = e0; ev.y = e1; ev.z = e2; ev.w = e3;
            *(float4*)(alpha_base + (size_t)(p * 8) * NN + mb) = ev;
        }
    }
    // ---- phase B: stage hT chunk [128 o][128 m], swizzled ----
#pragma unroll
    for (int q = 0; q < 8; ++q)
        *(bf16x8*)&hT_lds[(q * 16 + hrow0) * 128 + (hbyte >> 1)] = hv[q];

    __syncthreads();
    // ---- phase C: MFMA; wave = (rh row-half, ch col-half) ----
#pragma unroll
    for (int k = 0; k < 4; ++k) {
        int cbyte = (k * 64 + quad * 16) ^ (col << 4);
        bf16x8 af = *(const bf16x8*)&al_lds[(rh * 16 + col) * 128 + (cbyte >> 1)];
#pragma unroll
        for (int ot = 0; ot < 4; ++ot) {
            bf16x8 bfv = *(const bf16x8*)&hT_lds[(ch * 64 + ot * 16 + col) * 128 + (cbyte >> 1)];
            acc[ot] = __builtin_amdgcn_mfma_f32_16x16x32_bf16(af, bfv, acc[ot], 0, 0, 0);
        }
    }
    __syncthreads();   // MFMA reads done; LDS free for next phase A/B
}

template <bool WRITE_ALPHA>
__global__ __launch_bounds__(256) void k_attn_mfma(const int* __restrict__ adj,
                                                   const float* __restrict__ s_in,
                                                   const float* __restrict__ d_in_,
                                                   const float* __restrict__ dmax_,
                                                   const unsigned short* __restrict__ hT,
                                                   float* __restrict__ out_scr,
                                                   float* __restrict__ alpha_out,
                                                   float* __restrict__ Li_out) {
    __shared__ unsigned short al_lds[32 * 128];    // XOR-swizzled, no pad
    __shared__ unsigned short hT_lds[128 * 128];   // XOR-swizzled, no pad
    int tid = threadIdx.x;
    // XCD-aware bijective swizzle (1024 blocks % 8 XCDs == 0): XCD x owns
    // bids [x*128,(x+1)*128) == bh {2x, 2x+1} -> adj/hT L2-resident.
    int bid = (int)(blockIdx.x & 7) * 128 + (int)(blockIdx.x >> 3);
    int bh = bid >> 6;                  // 64 32-row tiles per bh
    int nb = (bid & 63) * 32;
    int b = bh >> 2;

    // phase-A mapping: 4 passes; pass p: row = p*8 + ar0, float-col = ac4..+3
    int ar0 = tid >> 5;                 // 0..7
    int ac4 = (tid & 31) * 4;           // 0..124
    const int* adj_base = adj + ((size_t)b * NN + nb + ar0) * NN + ac4;
    float* alpha_base = WRITE_ALPHA
        ? alpha_out + ((size_t)bh * NN + nb + ar0) * NN + ac4 : nullptr;
    const float* dg = d_in_ + (size_t)bh * NN;     // L2-hot 8 KB row

    // per-row stabilizer + s (rows p*8+ar0, shared by each 32-lane group)
    float dmx = dmax_[bh];
    float sreg[4], Mreg[4];
#pragma unroll
    for (int p = 0; p < 4; ++p) {
        sreg[p] = s_in[bh * NN + nb + p * 8 + ar0];
        float t = sreg[p] + dmx;
        Mreg[p] = t > 0.f ? t : 0.2f * t;
    }

    // ---------------- pass 1: row sums L (register-resident) ----------------
    float Lp[4];
#pragma unroll
    for (int p = 0; p < 4; ++p) Lp[p] = 0.f;
    {
        AdjD A0, A1;
        adjd_load(0, adj_base, dg, ac4, A0);
        for (int mb = 0; mb < NN; mb += 256) {
            adjd_load(mb + 128, adj_base, dg, ac4, A1);
            p1_accum(A0, sreg, Mreg, Lp);
            adjd_load((mb + 256) & (NN - 1), adj_base, dg, ac4, A0);
            p1_accum(A1, sreg, Mreg, Lp);
        }
    }
    // reduce across the 32 lanes sharing each row (xor stays in 32-halves)
#pragma unroll
    for (int off = 16; off >= 1; off >>= 1)
#pragma unroll
        for (int p = 0; p < 4; ++p)
            Lp[p] += __shfl_xor(Lp[p], off, 64);
    float Lin[4];
#pragma unroll
    for (int p = 0; p < 4; ++p) Lin[p] = Lp[p] > 0.f ? 1.f / Lp[p] : 0.f;
    if (!WRITE_ALPHA && (tid & 31) == 0) {
#pragma unroll
        for (int p = 0; p < 4; ++p)
            Li_out[bh * NN + nb + p * 8 + ar0] = Lin[p];
    }

    // ---------------- pass 2: alpha -> LDS -> MFMA (pipelined) --------------
    // phase-B mapping: 16 lanes x 16B = 256B contiguous per o-row
    int hrow0 = tid >> 4;               // 0..15
    int hcolu = (tid & 15) * 8;         // ushort col 0..120
    const unsigned short* hbase = hT + ((size_t)bh * DD + hrow0) * NN + hcolu;
    int hbyte = (hcolu * 2) ^ (hrow0 << 4);
    // phase-C mapping: wave -> (row half, col half); lane -> (col, quad)
    int l = tid & 63, w = tid >> 6, col = l & 15, quad = l >> 4;
    int rh = w & 1, ch = w >> 1;

    f32x4 acc[4];
#pragma unroll
    for (int ot = 0; ot < 4; ++ot) acc[ot] = (f32x4){0.f, 0.f, 0.f, 0.f};

    AdjD A0, A1;
    adjd_load(0, adj_base, dg, ac4, A0);

    for (int mb = 0; mb < NN; mb += 256) {
        attn_tile_body<WRITE_ALPHA>(mb, A0, A1, adj_base, dg, ac4, hbase,
                                    al_lds, hT_lds, sreg, Mreg, Lin,
                                    alpha_base, ar0, hrow0, hbyte,
                                    rh, ch, col, quad, acc);
        attn_tile_body<WRITE_ALPHA>(mb + 128, A1, A0, adj_base, dg, ac4, hbase,
                                    al_lds, hT_lds, sreg, Mreg, Lin,
                                    alpha_base, ar0, hrow0, hbyte,
                                    rh, ch, col, quad, acc);
    }
    // epilogue: C/D layout col=lane&15, row=quad*4+reg
#pragma unroll
    for (int ot = 0; ot < 4; ++ot)
#pragma unroll
        for (int r = 0; r < 4; ++r)
            out_scr[((size_t)bh * NN + nb + rh * 16 + quad * 4 + r) * DD
                    + ch * 64 + ot * 16 + col] = acc[ot][r];
}

// ---------------------------------------------------------------------------
// Kernel 4: output[b,n,o] = concat_h(out_scr) @ Wp + bias, fp32 store.
// ---------------------------------------------------------------------------
__global__ __launch_bounds__(256) void k_proj(const float* __restrict__ out_scr,
                                              const float* __restrict__ Wp,
                                              const float* __restrict__ bias,
                                              float* __restrict__ out) {
    __shared__ float cs[16 * 512];
    int tid = threadIdx.x;
    int b  = blockIdx.x / (NN / 16);
    int nb = (blockIdx.x % (NN / 16)) * 16;
    for (int idx = tid; idx < 16 * 512; idx += 256) {
        int r = idx >> 9, c = idx & 511;
        int hh = c >> 7, oo = c & 127;
        cs[idx] = out_scr[((size_t)(b * HH + hh) * NN + nb + r) * DD + oo];
    }
    __syncthreads();
    int o = tid & 63, rg = tid >> 6;        // 4 row-groups x 4 rows
    float bv0 = bias[o], bv1 = bias[o + 64];
    float acc0[4], acc1[4];
#pragma unroll
    for (int j = 0; j < 4; ++j) { acc0[j] = bv0; acc1[j] = bv1; }
    for (int k = 0; k < 512; k += 4) {
        float w00 = Wp[(k + 0) * DD + o], w01 = Wp[(k + 0) * DD + o + 64];
        float w10 = Wp[(k + 1) * DD + o], w11 = Wp[(k + 1) * DD + o + 64];
        float w20 = Wp[(k + 2) * DD + o], w21 = Wp[(k + 2) * DD + o + 64];
        float w30 = Wp[(k + 3) * DD + o], w31 = Wp[(k + 3) * DD + o + 64];
#pragma unroll
        for (int j = 0; j < 4; ++j) {
            float4 cq = *(const float4*)&cs[(rg * 4 + j) * 512 + k];
            acc0[j] += cq.x * w00 + cq.y * w10 + cq.z * w20 + cq.w * w30;
            acc1[j] += cq.x * w01 + cq.y * w11 + cq.z * w21 + cq.w * w31;
        }
    }
#pragma unroll
    for (int j = 0; j < 4; ++j) {
        out[((size_t)b * NN + nb + rg * 4 + j) * DD + o]      = acc0[j];
        out[((size_t)b * NN + nb + rg * 4 + j) * DD + o + 64] = acc1[j];
    }
}

// ---------------------------------------------------------------------------
// Kernel 5 (fallback only, ws too small): final fp32 alpha over scratch.
// ---------------------------------------------------------------------------
__global__ __launch_bounds__(256) void k_alpha(const int* __restrict__ adj,
                                               const float* __restrict__ s_in,
                                               const float* __restrict__ d_in_,
                                               const float* __restrict__ dmax_,
                                               const float* __restrict__ Li_in,
                                               float* __restrict__ alpha_out) {
    int tid = threadIdx.x;
    int b = blockIdx.x / NN, n = blockIdx.x % NN;
    float sv[4], Mv[4], Lv[4];
#pragma unroll
    for (int h = 0; h < 4; ++h) {
        sv[h] = s_in[(b * HH + h) * NN + n];
        float t = sv[h] + dmax_[b * HH + h];
        Mv[h] = t > 0.f ? t : 0.2f * t;
        Lv[h] = Li_in[(b * HH + h) * NN + n];
    }
    const int* arow = adj + ((size_t)b * NN + n) * NN;
    for (int m = tid; m < NN; m += 256) {
        int av = arow[m];
#pragma unroll
        for (int h = 0; h < 4; ++h) {
            float val = 0.f;
            if (av != 0) {
                float t = sv[h] + d_in_[(b * HH + h) * NN + m];
                float v = t > 0.f ? t : 0.2f * t;
                val = exp2f((v - Mv[h]) * LOG2E) * Lv[h];
            }
            alpha_out[((size_t)(b * HH + h) * NN + n) * NN + m] = val;
        }
    }
}

// ---------------------------------------------------------------------------
extern "C" void kernel_launch(void* const* d_in, const int* in_sizes, int n_in,
                              void* d_out, int out_size, void* d_ws, size_t ws_size,
                              hipStream_t stream) {
    const float* x    = (const float*)d_in[0];
    const int*   adj  = (const int*)d_in[1];
    const float* W    = (const float*)d_in[2];
    const float* a    = (const float*)d_in[3];
    const float* Wp   = (const float*)d_in[4];
    const float* bias = (const float*)d_in[5];

    float* out       = (float*)d_out;
    float* alpha_out = out + (size_t)BB * NN * DD;

    // Workspace head: stats + WT16.
    float* ws    = (float*)d_ws;
    float* wsv   = ws;
    float* wdv   = wsv + HH * DD;
    float* s_    = wdv + HH * DD;
    float* d_    = s_ + (size_t)BB * HH * NN;
    float* Li_   = d_ + (size_t)BB * HH * NN;
    float* dmax_ = Li_ + (size_t)BB * HH * NN;
    _Float16* WT16 = (_Float16*)(dmax_ + 16);

    const size_t stats_bytes = (2 * HH * DD + 3 * (size_t)BB * HH * NN + 16) * sizeof(float)
                             + (size_t)HH * DD * DD * sizeof(_Float16);   // +128 KB WT16
    const size_t hT_bytes    = (size_t)BB * HH * NN * DD * sizeof(unsigned short);  // 8.39 MB
    const size_t scr_bytes   = (size_t)BB * HH * NN * DD * sizeof(float);           // 16.8 MB
    const bool fused = ws_size >= stats_bytes + hT_bytes + scr_bytes;

    unsigned short* hT;
    float* out_scr;
    if (fused) {
        hT      = (unsigned short*)((char*)d_ws + stats_bytes);
        out_scr = (float*)((char*)hT + hT_bytes);
    } else {
        hT      = (unsigned short*)alpha_out;
        out_scr = alpha_out + (size_t)BB * HH * NN * DD;
    }

    k_prep<<<HH, 128, 0, stream>>>(W, a, wsv, wdv, WT16);
    k_sd<<<BB * NN / 64, 256, 0, stream>>>(x, wsv, wdv, s_, d_);
    k_h_mfma<<<BB * HH * (NN / 64), 256, 0, stream>>>(x, WT16, hT);
    k_dmax<<<BB * HH, 256, 0, stream>>>(d_, dmax_);
    if (fused) {
        k_attn_mfma<true><<<BB * HH * (NN / 32), 256, 0, stream>>>(adj, s_, d_, dmax_,
                                                                   hT, out_scr, alpha_out, Li_);
        k_proj<<<BB * (NN / 16), 256, 0, stream>>>(out_scr, Wp, bias, out);
    } else {
        k_attn_mfma<false><<<BB * HH * (NN / 32), 256, 0, stream>>>(adj, s_, d_, dmax_,
                                                                    hT, out_scr, alpha_out, Li_);
        k_proj<<<BB * (NN / 16), 256, 0, stream>>>(out_scr, Wp, bias, out);
        k_alpha<<<BB * NN, 256, 0, stream>>>(adj, s_, d_, dmax_, Li_, alpha_out);
    }
}